// Round 1
// 636.297 us; speedup vs baseline: 1.1135x; 1.1135x over previous
//
#include <hip/hip_runtime.h>
#include <hip/hip_bf16.h>

#define NNODES 100000
#define NEDGES 3200000
#define DIM    512
#define GF     4
#define HD     128

#define BM      128
#define BK      32
#define KSTEPS  (DIM / BK)          // 16
#define ABUF    (BM * BK)           // 4096 elems (8 KB)
#define BBUF    (DIM * BK)          // 16384 elems (32 KB)
#define LDSBUF  (ABUF + BBUF)       // 20480 elems (40 KB) per buffer

typedef __bf16 bf16x8 __attribute__((ext_vector_type(8)));
typedef float  f32x4  __attribute__((ext_vector_type(4)));

// ---------------- runtime dtype dispatch helpers ----------------
__device__ __forceinline__ float ldF(const void* p, size_t i, int isF32) {
    return isF32 ? ((const float*)p)[i]
                 : __bfloat162float(((const __hip_bfloat16*)p)[i]);
}
__device__ __forceinline__ void stF(void* p, size_t i, float v, int isF32) {
    if (isF32) ((float*)p)[i] = v;
    else       ((__hip_bfloat16*)p)[i] = __float2bfloat16(v);
}
__device__ __forceinline__ long long ldI(const void* p, size_t i, int isI64) {
    return isI64 ? ((const long long*)p)[i] : (long long)((const int*)p)[i];
}
// load 8 consecutive float-elements starting at elemOff, return as bf16x8
__device__ __forceinline__ bf16x8 ld8(const void* base, size_t elemOff, int isF32) {
    if (isF32) {
        const float* p = (const float*)base + elemOff;
        f32x4 a = *(const f32x4*)p;
        f32x4 b = *(const f32x4*)(p + 4);
        bf16x8 r;
        r[0] = (__bf16)a[0]; r[1] = (__bf16)a[1]; r[2] = (__bf16)a[2]; r[3] = (__bf16)a[3];
        r[4] = (__bf16)b[0]; r[5] = (__bf16)b[1]; r[6] = (__bf16)b[2]; r[7] = (__bf16)b[3];
        return r;
    }
    return *(const bf16x8*)((const __hip_bfloat16*)base + elemOff);
}

// async global->LDS, 16B per lane; lds ptr must be wave-uniform (dest = base + lane*16)
__device__ __forceinline__ void gload_lds16(const void* g, void* l) {
    __builtin_amdgcn_global_load_lds(
        (const __attribute__((address_space(1))) unsigned int*)g,
        (__attribute__((address_space(3))) unsigned int*)l,
        16, 0, 0);
}

// ---------------- D0: detect dtypes from buffer contents ----------------
__global__ void detect_kernel(const unsigned short* __restrict__ featU16,
                              const int* __restrict__ srcI32,
                              int* __restrict__ flags) {
    __shared__ int sF, sI;
    if (threadIdx.x == 0) { sF = 0; sI = 0; }
    __syncthreads();
    int cntF = 0, cntI = 0;
    for (int i = threadIdx.x; i < 8192; i += 256) {
        unsigned short u = featU16[i];
        int e = (u >> 7) & 0xFF;
        if (e >= 0xE0) cntF++;
        if ((i & 1) && srcI32[i] != 0) cntI++;
    }
    atomicAdd(&sF, cntF);
    atomicAdd(&sI, cntI);
    __syncthreads();
    if (threadIdx.x == 0) {
        flags[0] = (sF > 20) ? 1 : 0;
        flags[1] = (sI == 0) ? 1 : 0;
    }
}

// ---------- P1: Wt[col][d] = att[g,d] * W_lin[g,d,h]  (col=g*128+h), bf16 ----------
__global__ void prep_kernel(const void* __restrict__ att,
                            const void* __restrict__ W_lin,
                            __hip_bfloat16* __restrict__ Wt,
                            const int* __restrict__ flags) {
    const int isF32 = flags[0];
    int t = blockIdx.x * blockDim.x + threadIdx.x;   // 0..2047 = (g,d)
    int g = t >> 9, d = t & 511;
    float a = ldF(att, (size_t)g * DIM + d, isF32);
    size_t wbase = ((size_t)g * DIM + d) * HD;
    __hip_bfloat16* wt = Wt + (size_t)(g * HD) * DIM + d;
    for (int h = 0; h < HD; ++h) {
        float w = ldF(W_lin, wbase + h, isF32);
        wt[(size_t)h * DIM] = __float2bfloat16(a * w);
    }
}

// ---------- P2: cb[g] = b_al+b_ar + sum_h b_lin*(w_al+w_ar) ----------
__global__ void bias_kernel(const void* b_lin, const void* w_al, const void* b_al,
                            const void* w_ar, const void* b_ar,
                            float* cb, const int* __restrict__ flags) {
    const int isF32 = flags[0];
    int g = threadIdx.x;
    if (g < GF) {
        float s = ldF(b_al, g, isF32) + ldF(b_ar, g, isF32);
        for (int h = 0; h < HD; ++h) {
            float bl = ldF(b_lin, g * HD + h, isF32);
            s += bl * (ldF(w_al, g * HD + h, isF32) + ldF(w_ar, g * HD + h, isF32));
        }
        cb[g] = s;
    }
}

// ---------- GEMM: 128 rows x ALL 512 cols per block (feat read ONCE) ----------
// 512 thr = 8 waves in 2x4 grid; wave (waveM, g) owns rows [waveM*64,+64) x factor g.
// Double-buffered LDS, 1 barrier/K-step; B staged via global_load_lds (bf16),
// A reg-staged with issue-early/write-late split (f32->bf16 cvt in regs).
__global__ __launch_bounds__(512, 2) void gemm_kernel(
        const void* __restrict__ feat,
        const __hip_bfloat16* __restrict__ Wt,
        const void* __restrict__ b_lin,
        const void* __restrict__ w_al,
        const void* __restrict__ w_ar,
        void* __restrict__ out_hidden,
        float* __restrict__ a_l, float* __restrict__ a_r,
        const int* __restrict__ flags) {
    __shared__ __attribute__((aligned(16))) __hip_bfloat16 lds[2 * LDSBUF]; // 80 KB
    const int isF32 = flags[0];

    const int tid  = threadIdx.x;
    const int lane = tid & 63;
    const int wave = tid >> 6;          // 0..7
    const int q    = lane >> 4;
    const int lm   = lane & 15;
    const int waveM = wave >> 2;        // 0..1
    const int g     = wave & 3;         // factor handled by this wave
    const int rowBase = blockIdx.x * BM;

    // ---- staging geometry ----
    // A: thread -> chunk tid: row=tid>>2, kb=tid&3; LDS elem off = tid*8 (linear)
    const int sRow = tid >> 2;
    const int sKb  = tid & 3;
    const size_t gAoff = (size_t)min(rowBase + sRow, NNODES - 1) * DIM + sKb * 8;
    const int wbase = tid & ~63;        // wave-uniform chunk base

    // fragment read offsets (elements, within a buffer)
    const int aoffBase = (waveM * 64 + lm) * BK + q * 8;          // + mi*512
    const int boffBase = ABUF + (g * HD + lm) * BK + q * 8;       // + ni*512

    f32x4 acc[4][8];
#pragma unroll
    for (int mi = 0; mi < 4; ++mi)
#pragma unroll
        for (int ni = 0; ni < 8; ++ni) {
            f32x4 z = {0.f, 0.f, 0.f, 0.f};
            acc[mi][ni] = z;
        }

    // stage B (always) + A (bf16 path) for K-step ko into buffer buf
    auto stage = [&](int buf, int ko) {
#pragma unroll
        for (int j = 0; j < 4; ++j) {
            int c = j * 512 + tid;                         // B chunk: col=c>>2, kb=c&3
            const __hip_bfloat16* src = Wt + (size_t)(c >> 2) * DIM + ko * BK + (c & 3) * 8;
            gload_lds16(src, lds + buf * LDSBUF + ABUF + (size_t)(j * 512 + wbase) * 8);
        }
        if (!isF32) {
            const __hip_bfloat16* srcA = (const __hip_bfloat16*)feat + gAoff + (size_t)ko * BK;
            gload_lds16(srcA, lds + buf * LDSBUF + (size_t)wbase * 8);
        }
    };

    auto compute = [&](int buf) {
        const __hip_bfloat16* base = lds + buf * LDSBUF;
        bf16x8 af[4], bfr[8];
#pragma unroll
        for (int mi = 0; mi < 4; ++mi) af[mi] = *(const bf16x8*)(base + aoffBase + mi * 512);
#pragma unroll
        for (int ni = 0; ni < 8; ++ni) bfr[ni] = *(const bf16x8*)(base + boffBase + ni * 512);
#pragma unroll
        for (int mi = 0; mi < 4; ++mi)
#pragma unroll
            for (int ni = 0; ni < 8; ++ni)
                acc[mi][ni] = __builtin_amdgcn_mfma_f32_16x16x32_bf16(
                    af[mi], bfr[ni], acc[mi][ni], 0, 0, 0);
    };

    // prologue: fill buffer 0
    stage(0, 0);
    if (isF32) *(bf16x8*)(lds + tid * 8) = ld8(feat, gAoff, 1);
    __syncthreads();

    // main loop: compute buf cur while staging cur^1
    for (int t = 0; t < KSTEPS - 1; ++t) {
        const int cur = t & 1, nxt = cur ^ 1;
        stage(nxt, t + 1);                                 // issue loads early
        bf16x8 aNext;
        if (isF32) aNext = ld8(feat, gAoff + (size_t)(t + 1) * BK, 1);
        compute(cur);                                      // MFMA hides load latency
        if (isF32) *(bf16x8*)(lds + nxt * LDSBUF + tid * 8) = aNext;
        __syncthreads();                                   // drains vmcnt+lgkm, flips buffers
    }
    compute((KSTEPS - 1) & 1);

    // ---- epilogue: wave owns rows x full factor g -> direct a_l/a_r (no atomics) ----
    float wal[8], war[8], blin[8];
#pragma unroll
    for (int ni = 0; ni < 8; ++ni) {
        int col = ni * 16 + lm;
        wal[ni]  = ldF(w_al,  g * HD + col, isF32);
        war[ni]  = ldF(w_ar,  g * HD + col, isF32);
        blin[ni] = ldF(b_lin, g * HD + col, isF32);
    }
#pragma unroll
    for (int mi = 0; mi < 4; ++mi) {
        float sal[4] = {0.f, 0.f, 0.f, 0.f};
        float sar[4] = {0.f, 0.f, 0.f, 0.f};
#pragma unroll
        for (int r = 0; r < 4; ++r)
#pragma unroll
            for (int ni = 0; ni < 8; ++ni) {
                float v = acc[mi][ni][r];
                sal[r] += v * wal[ni];
                sar[r] += v * war[ni];
            }
        // reduce over the 16 lm lanes (full 128-col sum for factor g)
#pragma unroll
        for (int off = 1; off < 16; off <<= 1)
#pragma unroll
            for (int r = 0; r < 4; ++r) {
                sal[r] += __shfl_xor(sal[r], off, 64);
                sar[r] += __shfl_xor(sar[r], off, 64);
            }
#pragma unroll
        for (int r = 0; r < 4; ++r) {
            int row = rowBase + waveM * 64 + mi * 16 + q * 4 + r;   // C/D: row=q*4+reg
            if (row < NNODES) {
#pragma unroll
                for (int ni = 0; ni < 8; ++ni) {
                    int col = g * HD + ni * 16 + lm;                // C/D: col=lane&15
                    stF(out_hidden, (size_t)row * DIM + col,
                        acc[mi][ni][r] + blin[ni], isF32);
                }
                if (lm == 0) {
                    a_l[g * NNODES + row] = sal[r];
                    a_r[g * NNODES + row] = sar[r];
                }
            }
        }
    }
}

// ---------- edges: factors = sigmoid(a_l[src] + a_r[dst] + cb) ----------
__global__ __launch_bounds__(256) void edge_kernel(
        const void* __restrict__ src, const void* __restrict__ dst,
        const float* __restrict__ a_l, const float* __restrict__ a_r,
        const float* __restrict__ cb, void* __restrict__ out,
        const int* __restrict__ flags) {
    const int isF32 = flags[0];
    const int isI64 = flags[1];
    int e = blockIdx.x * 256 + threadIdx.x;
    if (e >= NEDGES) return;
    long long s = ldI(src, e, isI64);
    long long d = ldI(dst, e, isI64);
    const size_t base = (size_t)NNODES * DIM;
#pragma unroll
    for (int g = 0; g < GF; ++g) {
        float x = a_l[g * NNODES + s] + a_r[g * NNODES + d] + cb[g];
        float f = 1.0f / (1.0f + __expf(-x));   // SIGMA = 1.0
        stF(out, base + (size_t)g * NEDGES + e, f, isF32);
    }
}

extern "C" void kernel_launch(void* const* d_in, const int* in_sizes, int n_in,
                              void* d_out, int out_size, void* d_ws, size_t ws_size,
                              hipStream_t stream) {
    const void* feat  = d_in[0];
    const void* src   = d_in[1];
    const void* dst   = d_in[2];
    const void* att   = d_in[3];
    const void* W_lin = d_in[4];
    const void* b_lin = d_in[5];
    const void* w_al  = d_in[6];
    const void* b_al  = d_in[7];
    const void* w_ar  = d_in[8];
    const void* b_ar  = d_in[9];

    char* ws = (char*)d_ws;
    int*   flags = (int*)ws;                            // 8 B
    float* cb    = (float*)(ws + 16);                   // 16 B
    __hip_bfloat16* Wt = (__hip_bfloat16*)(ws + 1024);  // 512*512*2 = 524288 B
    float* a_l = (float*)(ws + 1024 + 524288);          // 1.6 MB
    float* a_r = (float*)(ws + 1024 + 524288 + 1600000);// 1.6 MB  (total ~3.73 MB)

    detect_kernel<<<1, 256, 0, stream>>>((const unsigned short*)feat, (const int*)src, flags);
    prep_kernel<<<8, 256, 0, stream>>>(att, W_lin, Wt, flags);
    bias_kernel<<<1, 64, 0, stream>>>(b_lin, w_al, b_al, w_ar, b_ar, cb, flags);

    gemm_kernel<<<dim3((NNODES + BM - 1) / BM), 512, 0, stream>>>(
        feat, Wt, b_lin, w_al, w_ar, d_out, a_l, a_r, flags);
    edge_kernel<<<NEDGES / 256, 256, 0, stream>>>(
        src, dst, a_l, a_r, cb, d_out, flags);
}

// Round 2
// 515.832 us; speedup vs baseline: 1.3735x; 1.2335x over previous
//
#include <hip/hip_runtime.h>
#include <hip/hip_bf16.h>

#define NNODES 100000
#define NEDGES 3200000
#define DIM    512
#define GF     4
#define HD     128

#define BM      128
#define BK      32
#define KSTEPS  (DIM / BK)          // 16

typedef __bf16 bf16x8 __attribute__((ext_vector_type(8)));
typedef float  f32x4  __attribute__((ext_vector_type(4)));

// ---------------- runtime dtype dispatch helpers ----------------
__device__ __forceinline__ float ldF(const void* p, size_t i, int isF32) {
    return isF32 ? ((const float*)p)[i]
                 : __bfloat162float(((const __hip_bfloat16*)p)[i]);
}
__device__ __forceinline__ void stF(void* p, size_t i, float v, int isF32) {
    if (isF32) ((float*)p)[i] = v;
    else       ((__hip_bfloat16*)p)[i] = __float2bfloat16(v);
}
__device__ __forceinline__ long long ldI(const void* p, size_t i, int isI64) {
    return isI64 ? ((const long long*)p)[i] : (long long)((const int*)p)[i];
}

// async global->LDS, 16B per lane; LDS dest = wave-uniform base + lane*16
__device__ __forceinline__ void gload_lds16(const void* g, void* l) {
    __builtin_amdgcn_global_load_lds(
        (const __attribute__((address_space(1))) unsigned int*)g,
        (__attribute__((address_space(3))) unsigned int*)l,
        16, 0, 0);
}

// ---------------- D0: detect dtypes from buffer contents ----------------
__global__ void detect_kernel(const unsigned short* __restrict__ featU16,
                              const int* __restrict__ srcI32,
                              int* __restrict__ flags) {
    __shared__ int sF, sI;
    if (threadIdx.x == 0) { sF = 0; sI = 0; }
    __syncthreads();
    int cntF = 0, cntI = 0;
    for (int i = threadIdx.x; i < 8192; i += 1024) {
        unsigned short u = featU16[i];
        int e = (u >> 7) & 0xFF;
        if (e >= 0xE0) cntF++;
        if ((i & 1) && srcI32[i] != 0) cntI++;
    }
    atomicAdd(&sF, cntF);
    atomicAdd(&sI, cntI);
    __syncthreads();
    if (threadIdx.x == 0) {
        flags[0] = (sF > 20) ? 1 : 0;
        flags[1] = (sI == 0) ? 1 : 0;
    }
}

// ---------- P1: Wt[col][d] = att[g,d] * W_lin[g,d,h]  (col=g*128+h), bf16 ----------
// 128 blocks = (g, h-chunk of 4): 16x more parallelism than before; stores coalesced in d.
__global__ void prep_kernel(const void* __restrict__ att,
                            const void* __restrict__ W_lin,
                            __hip_bfloat16* __restrict__ Wt,
                            const int* __restrict__ flags) {
    const int isF32 = flags[0];
    const int g  = blockIdx.x >> 5;
    const int hc = blockIdx.x & 31;          // h range [hc*4, hc*4+4)
#pragma unroll
    for (int dh = 0; dh < 2; ++dh) {
        int d = threadIdx.x + dh * 256;
        float a = ldF(att, (size_t)g * DIM + d, isF32);
        size_t wbase = ((size_t)g * DIM + d) * HD;
#pragma unroll
        for (int j = 0; j < 4; ++j) {
            int h = hc * 4 + j;
            float w = ldF(W_lin, wbase + h, isF32);
            Wt[(size_t)(g * HD + h) * DIM + d] = __float2bfloat16(a * w);
        }
    }
}

// ---------- P2: cb[g] = b_al+b_ar + sum_h b_lin*(w_al+w_ar) ----------
__global__ void bias_kernel(const void* b_lin, const void* w_al, const void* b_al,
                            const void* w_ar, const void* b_ar,
                            float* cb, const int* __restrict__ flags) {
    const int isF32 = flags[0];
    int g = threadIdx.x;
    if (g < GF) {
        float s = ldF(b_al, g, isF32) + ldF(b_ar, g, isF32);
        for (int h = 0; h < HD; ++h) {
            float bl = ldF(b_lin, g * HD + h, isF32);
            s += bl * (ldF(w_al, g * HD + h, isF32) + ldF(w_ar, g * HD + h, isF32));
        }
        cb[g] = s;
    }
}

// ================= GEMM body: triple-buffered, counted-vmcnt pipeline =================
// 128 rows x 512 cols per block; 8 waves (2 waveM x 4 g). All staging via
// global_load_lds (A kept f32 in LDS on the f32 path, cvt at frag read).
// XOR-swizzled granule layout (pre-swizzled global source + swizzled read:
// both sides same involution, LDS dest linear -- rule 21 / m173).
template<int ISF32>
__device__ __forceinline__ void gemm_body(
        const void* __restrict__ feat,
        const __hip_bfloat16* __restrict__ Wt,
        const void* __restrict__ b_lin,
        const void* __restrict__ w_al,
        const void* __restrict__ w_ar,
        void* __restrict__ out_hidden,
        float* __restrict__ al4, float* __restrict__ ar4,
        char* lds) {
    constexpr int ABYTES = ISF32 ? 16384 : 8192;   // A tile: 128x32 f32 | bf16
    constexpr int LDSB   = ABYTES + 32768;         // + B tile 512x32 bf16

    const int tid  = threadIdx.x;
    const int lane = tid & 63;
    const int wave = tid >> 6;
    const int q    = lane >> 4;
    const int lm   = lane & 15;
    const int waveM = wave >> 2;
    const int g     = wave & 3;
    const int rowBase = blockIdx.x * BM;
    const int wbase = tid & ~63;

    // ---- swizzled read offsets (bytes within one buffer), loop-invariant ----
    int offA[4][2]; int offAb[4]; int offB[8];
#pragma unroll
    for (int mi = 0; mi < 4; ++mi) {
        int row = waveM * 64 + mi * 16 + lm;
        if (ISF32) {  // granule = row*8 + (kc ^ (row&7)), kc = 2q, 2q+1
            offA[mi][0] = (row * 8 + ((2 * q)     ^ (row & 7))) * 16;
            offA[mi][1] = (row * 8 + ((2 * q + 1) ^ (row & 7))) * 16;
        } else {      // granule = row*4 + (q ^ ((row>>1)&3))
            offAb[mi]   = (row * 4 + (q ^ ((row >> 1) & 3))) * 16;
        }
    }
#pragma unroll
    for (int ni = 0; ni < 8; ++ni) {
        int col = g * HD + ni * 16 + lm;
        offB[ni] = ABYTES + (col * 4 + (q ^ ((col >> 1) & 3))) * 16;
    }

    // ---- staging sources (pre-swizzled global addrs) + linear LDS dests ----
    const __hip_bfloat16* srcB[4]; int dstB[4];
#pragma unroll
    for (int j = 0; j < 4; ++j) {
        int c = j * 512 + tid, col = c >> 2, qs = c & 3;
        int ql = qs ^ ((col >> 1) & 3);
        srcB[j] = Wt + (size_t)col * DIM + ql * 8;
        dstB[j] = ABYTES + (j * 512 + wbase) * 16;
    }
    const float* srcAf0 = nullptr; const float* srcAf1 = nullptr;
    const __hip_bfloat16* srcAb = nullptr;
    int dstA0 = 0, dstA1 = 0;
    if constexpr (ISF32) {
        {   int G = tid, row = G >> 3, kc = (G & 7) ^ (row & 7);
            srcAf0 = (const float*)feat + (size_t)min(rowBase + row, NNODES - 1) * DIM + kc * 4;
            dstA0 = wbase * 16; }
        {   int G = 512 + tid, row = G >> 3, kc = (G & 7) ^ (row & 7);
            srcAf1 = (const float*)feat + (size_t)min(rowBase + row, NNODES - 1) * DIM + kc * 4;
            dstA1 = (512 + wbase) * 16; }
    } else {
        int row = tid >> 2, ql = (tid & 3) ^ ((row >> 1) & 3);
        srcAb = (const __hip_bfloat16*)feat + (size_t)min(rowBase + row, NNODES - 1) * DIM + ql * 8;
        dstA0 = wbase * 16;
    }

    f32x4 acc[4][8];
#pragma unroll
    for (int mi = 0; mi < 4; ++mi)
#pragma unroll
        for (int ni = 0; ni < 8; ++ni) {
            f32x4 z = {0.f, 0.f, 0.f, 0.f};
            acc[mi][ni] = z;
        }

    auto stage = [&](int buf, int ko) {
        char* bb = lds + buf * LDSB;
#pragma unroll
        for (int j = 0; j < 4; ++j)
            gload_lds16(srcB[j] + (size_t)ko * BK, bb + dstB[j]);
        if constexpr (ISF32) {
            gload_lds16(srcAf0 + (size_t)ko * BK, bb + dstA0);
            gload_lds16(srcAf1 + (size_t)ko * BK, bb + dstA1);
        } else {
            gload_lds16(srcAb + (size_t)ko * BK, bb + dstA0);
        }
    };

    auto compute = [&](int buf) {
        const char* bb = lds + buf * LDSB;
        bf16x8 af[4];
#pragma unroll
        for (int mi = 0; mi < 4; ++mi) {
            if constexpr (ISF32) {
                f32x4 lo = *(const f32x4*)(bb + offA[mi][0]);
                f32x4 hi = *(const f32x4*)(bb + offA[mi][1]);
                bf16x8 a;
                a[0] = (__bf16)lo[0]; a[1] = (__bf16)lo[1];
                a[2] = (__bf16)lo[2]; a[3] = (__bf16)lo[3];
                a[4] = (__bf16)hi[0]; a[5] = (__bf16)hi[1];
                a[6] = (__bf16)hi[2]; a[7] = (__bf16)hi[3];
                af[mi] = a;
            } else {
                af[mi] = *(const bf16x8*)(bb + offAb[mi]);
            }
        }
        bf16x8 bfr[8];
#pragma unroll
        for (int ni = 0; ni < 8; ++ni) bfr[ni] = *(const bf16x8*)(bb + offB[ni]);
        __builtin_amdgcn_s_setprio(1);
#pragma unroll
        for (int mi = 0; mi < 4; ++mi)
#pragma unroll
            for (int ni = 0; ni < 8; ++ni)
                acc[mi][ni] = __builtin_amdgcn_mfma_f32_16x16x32_bf16(
                    af[mi], bfr[ni], acc[mi][ni], 0, 0, 0);
        __builtin_amdgcn_s_setprio(0);
    };

    // ---- pipeline: depth-2 prefetch, counted vmcnt (never 0 in loop) ----
    asm volatile("s_waitcnt vmcnt(0)" ::: "memory");   // drain strays: our counts start clean
    stage(0, 0);
    stage(1, 1);
    for (int t = 0; t < KSTEPS - 1; ++t) {
        // stage t's loads done (stage t+1's NLOADS may stay in flight across barrier)
        if constexpr (ISF32) asm volatile("s_waitcnt vmcnt(6)" ::: "memory");
        else                 asm volatile("s_waitcnt vmcnt(5)" ::: "memory");
        __builtin_amdgcn_sched_barrier(0);
        __builtin_amdgcn_s_barrier();                  // raw barrier: no implicit drain
        __builtin_amdgcn_sched_barrier(0);
        if (t + 2 < KSTEPS) stage((t + 2) % 3, t + 2); // overwrites buf (t-1)%3: safe, all waves past barrier
        compute(t % 3);
    }
    asm volatile("s_waitcnt vmcnt(0)" ::: "memory");
    __builtin_amdgcn_sched_barrier(0);
    __builtin_amdgcn_s_barrier();
    __builtin_amdgcn_sched_barrier(0);
    compute((KSTEPS - 1) % 3);

    // ---- epilogue: wave owns 64 rows x factor g -> direct a_l/a_r ----
    const int isF32 = ISF32;
    float wal[8], war[8], blin[8];
#pragma unroll
    for (int ni = 0; ni < 8; ++ni) {
        int col = ni * 16 + lm;
        wal[ni]  = ldF(w_al,  g * HD + col, isF32);
        war[ni]  = ldF(w_ar,  g * HD + col, isF32);
        blin[ni] = ldF(b_lin, g * HD + col, isF32);
    }
#pragma unroll
    for (int mi = 0; mi < 4; ++mi) {
        float sal[4] = {0.f, 0.f, 0.f, 0.f};
        float sar[4] = {0.f, 0.f, 0.f, 0.f};
#pragma unroll
        for (int r = 0; r < 4; ++r)
#pragma unroll
            for (int ni = 0; ni < 8; ++ni) {
                float v = acc[mi][ni][r];
                sal[r] += v * wal[ni];
                sar[r] += v * war[ni];
            }
#pragma unroll
        for (int off = 1; off < 16; off <<= 1)
#pragma unroll
            for (int r = 0; r < 4; ++r) {
                sal[r] += __shfl_xor(sal[r], off, 64);
                sar[r] += __shfl_xor(sar[r], off, 64);
            }
#pragma unroll
        for (int r = 0; r < 4; ++r) {
            int row = rowBase + waveM * 64 + mi * 16 + q * 4 + r;   // C/D: row=q*4+reg
            if (row < NNODES) {
#pragma unroll
                for (int ni = 0; ni < 8; ++ni) {
                    int col = g * HD + ni * 16 + lm;                // C/D: col=lane&15
                    stF(out_hidden, (size_t)row * DIM + col,
                        acc[mi][ni][r] + blin[ni], isF32);
                }
                if (lm == 0) {
                    al4[(size_t)row * 4 + g] = sal[r];   // packed [node][g] for edge gathers
                    ar4[(size_t)row * 4 + g] = sar[r];
                }
            }
        }
    }
}

__global__ __launch_bounds__(512, 2) void gemm_kernel(
        const void* __restrict__ feat,
        const __hip_bfloat16* __restrict__ Wt,
        const void* __restrict__ b_lin,
        const void* __restrict__ w_al,
        const void* __restrict__ w_ar,
        void* __restrict__ out_hidden,
        float* __restrict__ a_l, float* __restrict__ a_r,
        const int* __restrict__ flags) {
    __shared__ __attribute__((aligned(16))) char lds[3 * (16384 + 32768)];  // 144 KB
    if (flags[0])
        gemm_body<1>(feat, Wt, b_lin, w_al, w_ar, out_hidden, a_l, a_r, lds);
    else
        gemm_body<0>(feat, Wt, b_lin, w_al, w_ar, out_hidden, a_l, a_r, lds);
}

// ---------- edges: factors = sigmoid(a_l[src] + a_r[dst] + cb) ----------
// a_l/a_r packed [node][4]: one 16B gather per endpoint (4x fewer line fetches).
__global__ __launch_bounds__(256) void edge_kernel(
        const void* __restrict__ src, const void* __restrict__ dst,
        const float* __restrict__ a_l, const float* __restrict__ a_r,
        const float* __restrict__ cb, void* __restrict__ out,
        const int* __restrict__ flags) {
    const int isF32 = flags[0];
    const int isI64 = flags[1];
    int e = blockIdx.x * 256 + threadIdx.x;
    if (e >= NEDGES) return;
    long long s = ldI(src, e, isI64);
    long long d = ldI(dst, e, isI64);
    f32x4 va  = *(const f32x4*)(a_l + (size_t)s * 4);
    f32x4 vb  = *(const f32x4*)(a_r + (size_t)d * 4);
    f32x4 vcb = *(const f32x4*)cb;
    const size_t base = (size_t)NNODES * DIM;
#pragma unroll
    for (int g = 0; g < GF; ++g) {
        float x = va[g] + vb[g] + vcb[g];
        float f = 1.0f / (1.0f + __expf(-x));   // SIGMA = 1.0
        stF(out, base + (size_t)g * NEDGES + e, f, isF32);
    }
}

extern "C" void kernel_launch(void* const* d_in, const int* in_sizes, int n_in,
                              void* d_out, int out_size, void* d_ws, size_t ws_size,
                              hipStream_t stream) {
    const void* feat  = d_in[0];
    const void* src   = d_in[1];
    const void* dst   = d_in[2];
    const void* att   = d_in[3];
    const void* W_lin = d_in[4];
    const void* b_lin = d_in[5];
    const void* w_al  = d_in[6];
    const void* b_al  = d_in[7];
    const void* w_ar  = d_in[8];
    const void* b_ar  = d_in[9];

    char* ws = (char*)d_ws;
    int*   flags = (int*)ws;                            // 8 B
    float* cb    = (float*)(ws + 16);                   // 16 B (16B-aligned)
    __hip_bfloat16* Wt = (__hip_bfloat16*)(ws + 1024);  // 512*512*2 = 524288 B
    float* a_l = (float*)(ws + 1024 + 524288);          // [node][4] 1.6 MB
    float* a_r = (float*)(ws + 1024 + 524288 + 1600000);// [node][4] 1.6 MB

    detect_kernel<<<1, 1024, 0, stream>>>((const unsigned short*)feat, (const int*)src, flags);
    prep_kernel<<<128, 256, 0, stream>>>(att, W_lin, Wt, flags);
    bias_kernel<<<1, 64, 0, stream>>>(b_lin, w_al, b_al, w_ar, b_ar, cb, flags);

    gemm_kernel<<<dim3((NNODES + BM - 1) / BM), 512, 0, stream>>>(
        feat, Wt, b_lin, w_al, w_ar, d_out, a_l, a_r, flags);
    edge_kernel<<<NEDGES / 256, 256, 0, stream>>>(
        src, dst, a_l, a_r, cb, d_out, flags);
}